// Round 1
// baseline (101.608 us; speedup 1.0000x reference)
//
#include <hip/hip_runtime.h>
#include <hip/hip_bf16.h>
#include <cstdint>
#include <cstddef>

#define SEQD 20
#define HID  512
#define NB   4
#define LSEQ 2048
#define MROWS (NB * LSEQ)   // 8192

// ---------------------------------------------------------------------------
// Kernel 1: h1 = relu(X @ W1 + b1)   X:[M,20]  W1:[20,512]  -> h1:[M,512]
// 16 rows per block; each thread computes a 4-row x 4-col x 2-group micro-tile
// so W1 is read once per 4 rows (L2-hot, ~84 MB total).
// ---------------------------------------------------------------------------
__global__ __launch_bounds__(256) void k_enc1(const float* __restrict__ X,
                                              const float* __restrict__ W1,
                                              const float* __restrict__ b1,
                                              float* __restrict__ h1) {
  __shared__ float Xs[16][SEQD + 1];
  const int t = threadIdx.x;
  const int base = blockIdx.x * 16;
  for (int i = t; i < 16 * SEQD; i += 256) Xs[i / SEQD][i % SEQD] = X[base * SEQD + i];
  __syncthreads();

  const int m0 = (t >> 6) * 4;        // 0,4,8,12
  const int nl = (t & 63) * 4;        // 0..252 (plus +256 group)
  float4 acc[4][2];
#pragma unroll
  for (int mi = 0; mi < 4; ++mi) {
    acc[mi][0] = *(const float4*)&b1[nl];
    acc[mi][1] = *(const float4*)&b1[nl + 256];
  }
#pragma unroll
  for (int k = 0; k < SEQD; ++k) {
    const float4 w0 = *(const float4*)&W1[k * HID + nl];
    const float4 w1 = *(const float4*)&W1[k * HID + nl + 256];
#pragma unroll
    for (int mi = 0; mi < 4; ++mi) {
      const float xv = Xs[m0 + mi][k];
      acc[mi][0].x += xv * w0.x; acc[mi][0].y += xv * w0.y;
      acc[mi][0].z += xv * w0.z; acc[mi][0].w += xv * w0.w;
      acc[mi][1].x += xv * w1.x; acc[mi][1].y += xv * w1.y;
      acc[mi][1].z += xv * w1.z; acc[mi][1].w += xv * w1.w;
    }
  }
#pragma unroll
  for (int mi = 0; mi < 4; ++mi) {
#pragma unroll
    for (int g = 0; g < 2; ++g) {
      float4 r = acc[mi][g];
      r.x = fmaxf(r.x, 0.f); r.y = fmaxf(r.y, 0.f);
      r.z = fmaxf(r.z, 0.f); r.w = fmaxf(r.w, 0.f);
      *(float4*)&h1[(size_t)(base + m0 + mi) * HID + nl + g * 256] = r;
    }
  }
}

// ---------------------------------------------------------------------------
// Kernel 2: h = relu(h1 @ W2 + b2)   [8192,512] x [512,512], fp32 VALU GEMM.
// BM=64 BN=64 BK=32, 256 threads, 4x4 micro-tile, LDS A transposed for
// float4 reads. (fp32 has no MFMA on CDNA4 — bf16 MFMA is next round.)
// ---------------------------------------------------------------------------
__global__ __launch_bounds__(256) void k_gemm2(const float* __restrict__ A,
                                               const float* __restrict__ W2,
                                               const float* __restrict__ b2,
                                               float* __restrict__ Hout) {
  __shared__ float As[32][68];   // [k][m], padded
  __shared__ float Bs[32][68];   // [k][n], padded
  const int t  = threadIdx.x;
  const int bm = blockIdx.y * 64;
  const int bn = blockIdx.x * 64;
  const int tm = (t >> 4) * 4;
  const int tn = (t & 15) * 4;
  const int ar = t >> 3;           // 0..31
  const int ac = (t & 7) * 4;      // 0..28
  const int br = t >> 4;           // 0..15
  const int bc = (t & 15) * 4;     // 0..60

  float acc[4][4] = {};

  for (int k0 = 0; k0 < HID; k0 += 32) {
    const float4 a0  = *(const float4*)&A[(size_t)(bm + ar) * HID + k0 + ac];
    const float4 a1  = *(const float4*)&A[(size_t)(bm + ar + 32) * HID + k0 + ac];
    const float4 bv0 = *(const float4*)&W2[(size_t)(k0 + br) * HID + bn + bc];
    const float4 bv1 = *(const float4*)&W2[(size_t)(k0 + br + 16) * HID + bn + bc];
    __syncthreads();   // previous iteration's reads complete before overwrite
    As[ac + 0][ar] = a0.x; As[ac + 1][ar] = a0.y; As[ac + 2][ar] = a0.z; As[ac + 3][ar] = a0.w;
    As[ac + 0][ar + 32] = a1.x; As[ac + 1][ar + 32] = a1.y;
    As[ac + 2][ar + 32] = a1.z; As[ac + 3][ar + 32] = a1.w;
    *(float4*)&Bs[br][bc]      = bv0;
    *(float4*)&Bs[br + 16][bc] = bv1;
    __syncthreads();
#pragma unroll
    for (int k = 0; k < 32; ++k) {
      const float4 av = *(const float4*)&As[k][tm];
      const float4 bv = *(const float4*)&Bs[k][tn];
      acc[0][0] += av.x * bv.x; acc[0][1] += av.x * bv.y; acc[0][2] += av.x * bv.z; acc[0][3] += av.x * bv.w;
      acc[1][0] += av.y * bv.x; acc[1][1] += av.y * bv.y; acc[1][2] += av.y * bv.z; acc[1][3] += av.y * bv.w;
      acc[2][0] += av.z * bv.x; acc[2][1] += av.z * bv.y; acc[2][2] += av.z * bv.z; acc[2][3] += av.z * bv.w;
      acc[3][0] += av.w * bv.x; acc[3][1] += av.w * bv.y; acc[3][2] += av.w * bv.z; acc[3][3] += av.w * bv.w;
    }
  }

  const float4 bb = *(const float4*)&b2[bn + tn];
#pragma unroll
  for (int i = 0; i < 4; ++i) {
    float4 r;
    r.x = fmaxf(acc[i][0] + bb.x, 0.f);
    r.y = fmaxf(acc[i][1] + bb.y, 0.f);
    r.z = fmaxf(acc[i][2] + bb.z, 0.f);
    r.w = fmaxf(acc[i][3] + bb.w, 0.f);
    *(float4*)&Hout[(size_t)(bm + tm + i) * HID + bn + tn] = r;
  }
}

// ---------------------------------------------------------------------------
// Kernel 3: heads. One wave per row: ss softmax(3), angles(2), ci, cj.
// ---------------------------------------------------------------------------
__global__ __launch_bounds__(256) void k_heads(const float* __restrict__ Hm,
                                               const float* __restrict__ Wss,
                                               const float* __restrict__ bss,
                                               const float* __restrict__ Wang,
                                               const float* __restrict__ bang,
                                               const float* __restrict__ Wc,
                                               float* __restrict__ ssO,
                                               float* __restrict__ angO,
                                               float* __restrict__ ci,
                                               float* __restrict__ cj) {
  const int lane = threadIdx.x & 63;
  const int row  = blockIdx.x * 4 + (threadIdx.x >> 6);
  const float* hr = Hm + (size_t)row * HID;
  const float4 h0 = *(const float4*)&hr[lane * 8];
  const float4 h1 = *(const float4*)&hr[lane * 8 + 4];
  const float hv[8] = {h0.x, h0.y, h0.z, h0.w, h1.x, h1.y, h1.z, h1.w};

  float s0 = 0, s1 = 0, s2 = 0, a0 = 0, a1 = 0, c0 = 0, c1 = 0;
#pragma unroll
  for (int j = 0; j < 8; ++j) {
    const int k = lane * 8 + j;
    const float h = hv[j];
    s0 += h * Wss[k * 3 + 0];
    s1 += h * Wss[k * 3 + 1];
    s2 += h * Wss[k * 3 + 2];
    a0 += h * Wang[k * 2 + 0];
    a1 += h * Wang[k * 2 + 1];
    c0 += h * Wc[k];
    c1 += h * Wc[HID + k];
  }
#pragma unroll
  for (int off = 32; off > 0; off >>= 1) {
    s0 += __shfl_down(s0, off); s1 += __shfl_down(s1, off); s2 += __shfl_down(s2, off);
    a0 += __shfl_down(a0, off); a1 += __shfl_down(a1, off);
    c0 += __shfl_down(c0, off); c1 += __shfl_down(c1, off);
  }
  if (lane == 0) {
    const float l0 = s0 + bss[0], l1 = s1 + bss[1], l2 = s2 + bss[2];
    const float mx = fmaxf(l0, fmaxf(l1, l2));
    const float e0 = expf(l0 - mx), e1 = expf(l1 - mx), e2 = expf(l2 - mx);
    const float inv = 1.f / (e0 + e1 + e2);
    ssO[row * 3 + 0] = e0 * inv;
    ssO[row * 3 + 1] = e1 * inv;
    ssO[row * 3 + 2] = e2 * inv;
    angO[row * 2 + 0] = a0 + bang[0];
    angO[row * 2 + 1] = a1 + bang[1];
    ci[row] = c0;
    cj[row] = c1;
  }
}

// ---------------------------------------------------------------------------
// Kernel 4: contact[b,i,j] = sigmoid(ci[b,i] + cj[b,j] + bc). 67 MB write.
// One block per (b,i) row; 8 outputs/thread via float4 x2.
// ---------------------------------------------------------------------------
__global__ __launch_bounds__(256) void k_contact(const float* __restrict__ ci,
                                                 const float* __restrict__ cj,
                                                 const float* __restrict__ bc,
                                                 float* __restrict__ out) {
  const int row = blockIdx.x;          // b*2048 + i
  const int b   = row >> 11;
  const float base = ci[row] + bc[0];
  const float* cjb = cj + ((size_t)b << 11);
  float* orow = out + (size_t)row * LSEQ;
  const int j0 = threadIdx.x * 8;
  const float4 c0 = *(const float4*)&cjb[j0];
  const float4 c1 = *(const float4*)&cjb[j0 + 4];
  float4 r0, r1;
  r0.x = 1.f / (1.f + __expf(-(base + c0.x)));
  r0.y = 1.f / (1.f + __expf(-(base + c0.y)));
  r0.z = 1.f / (1.f + __expf(-(base + c0.z)));
  r0.w = 1.f / (1.f + __expf(-(base + c0.w)));
  r1.x = 1.f / (1.f + __expf(-(base + c1.x)));
  r1.y = 1.f / (1.f + __expf(-(base + c1.y)));
  r1.z = 1.f / (1.f + __expf(-(base + c1.z)));
  r1.w = 1.f / (1.f + __expf(-(base + c1.w)));
  *(float4*)&orow[j0]     = r0;
  *(float4*)&orow[j0 + 4] = r1;
}

// ---------------------------------------------------------------------------
extern "C" void kernel_launch(void* const* d_in, const int* in_sizes, int n_in,
                              void* d_out, int out_size, void* d_ws, size_t ws_size,
                              hipStream_t stream) {
  const float* X    = (const float*)d_in[0];
  const float* W1   = (const float*)d_in[1];
  const float* b1   = (const float*)d_in[2];
  const float* W2   = (const float*)d_in[3];
  const float* b2   = (const float*)d_in[4];
  const float* Wss  = (const float*)d_in[5];
  const float* bss  = (const float*)d_in[6];
  const float* Wang = (const float*)d_in[7];
  const float* bang = (const float*)d_in[8];
  const float* Wc   = (const float*)d_in[9];
  const float* bc   = (const float*)d_in[10];

  float* out     = (float*)d_out;
  float* ssO     = out;                         // [8192,3]  = 24576
  float* angO    = out + 24576;                 // [8192,2]  = 16384
  float* contact = out + 40960;                 // [4,2048,2048] = 16777216

  // Scratch: h1 and h live inside the (not-yet-written) contact region.
  // Contact kernel runs last and fully overwrites it. ci/cj (64 KB) in d_ws.
  float* h1 = contact;                          // 8192*512 floats = 16 MB
  float* hh = contact + (size_t)MROWS * HID;    // next 16 MB
  float* ci = (float*)d_ws;                     // 8192 floats
  float* cj = ci + MROWS;                       // 8192 floats

  k_enc1<<<MROWS / 16, 256, 0, stream>>>(X, W1, b1, h1);
  k_gemm2<<<dim3(HID / 64, MROWS / 64), 256, 0, stream>>>(h1, W2, b2, hh);
  k_heads<<<MROWS / 4, 256, 0, stream>>>(hh, Wss, bss, Wang, bang, Wc,
                                         ssO, angO, ci, cj);
  k_contact<<<MROWS, 256, 0, stream>>>(ci, cj, bc, contact);
}

// Round 2
// 58.570 us; speedup vs baseline: 1.7348x; 1.7348x over previous
//
#include <hip/hip_runtime.h>
#include <hip/hip_bf16.h>
#include <cstdint>
#include <cstddef>

#define SEQD 20
#define HID  512
#define LSEQ 2048
#define MROWS 8192

typedef __attribute__((ext_vector_type(4))) float f32x4;
typedef __attribute__((ext_vector_type(8))) short bf16x8;

__device__ __forceinline__ ushort f2bf(float f) {
  union { float f; unsigned u; } v; v.f = f;
  unsigned r = v.u + 0x7fffu + ((v.u >> 16) & 1u);   // RNE
  return (ushort)(r >> 16);
}
__device__ __forceinline__ float bf2f(ushort b) {
  union { unsigned u; float f; } v; v.u = ((unsigned)b) << 16;
  return v.f;
}
// async global->LDS, 16B per lane. LDS dest must be wave-uniform base;
// HW adds lane*16B (guide §5: wave-uniform base + lane*size).
__device__ __forceinline__ void async16(const ushort* g, ushort* l) {
  __builtin_amdgcn_global_load_lds(
      (const __attribute__((address_space(1))) unsigned*)g,
      (__attribute__((address_space(3))) unsigned*)l, 16, 0, 0);
}

// ---------------------------------------------------------------------------
// Kernel 1: h1 = relu(X @ W1 + b1) -> bf16  [M,512]
// ---------------------------------------------------------------------------
__global__ __launch_bounds__(256) void k_enc1(const float* __restrict__ X,
                                              const float* __restrict__ W1,
                                              const float* __restrict__ b1,
                                              ushort* __restrict__ h1) {
  __shared__ float Xs[16][SEQD + 1];
  const int t = threadIdx.x;
  const int base = blockIdx.x * 16;
  for (int i = t; i < 16 * SEQD; i += 256) Xs[i / SEQD][i % SEQD] = X[base * SEQD + i];
  __syncthreads();

  const int m0 = (t >> 6) * 4;
  const int nl = (t & 63) * 4;
  float4 acc[4][2];
#pragma unroll
  for (int mi = 0; mi < 4; ++mi) {
    acc[mi][0] = *(const float4*)&b1[nl];
    acc[mi][1] = *(const float4*)&b1[nl + 256];
  }
#pragma unroll
  for (int k = 0; k < SEQD; ++k) {
    const float4 w0 = *(const float4*)&W1[k * HID + nl];
    const float4 w1 = *(const float4*)&W1[k * HID + nl + 256];
#pragma unroll
    for (int mi = 0; mi < 4; ++mi) {
      const float xv = Xs[m0 + mi][k];
      acc[mi][0].x += xv * w0.x; acc[mi][0].y += xv * w0.y;
      acc[mi][0].z += xv * w0.z; acc[mi][0].w += xv * w0.w;
      acc[mi][1].x += xv * w1.x; acc[mi][1].y += xv * w1.y;
      acc[mi][1].z += xv * w1.z; acc[mi][1].w += xv * w1.w;
    }
  }
#pragma unroll
  for (int mi = 0; mi < 4; ++mi) {
#pragma unroll
    for (int g = 0; g < 2; ++g) {
      const float4 r = acc[mi][g];
      ushort4 o;
      o.x = f2bf(fmaxf(r.x, 0.f)); o.y = f2bf(fmaxf(r.y, 0.f));
      o.z = f2bf(fmaxf(r.z, 0.f)); o.w = f2bf(fmaxf(r.w, 0.f));
      *(ushort4*)&h1[(size_t)(base + m0 + mi) * HID + nl + g * 256] = o;
    }
  }
}

// ---------------------------------------------------------------------------
// Kernel 1b: W2 [K=512][N=512] f32  ->  W2t [N][K] bf16 (transpose+convert)
// so the GEMM B-fragment is a contiguous ds_read_b128 (m92 B^T trick).
// ---------------------------------------------------------------------------
__global__ __launch_bounds__(256) void k_cvtW2(const float* __restrict__ W2,
                                               ushort* __restrict__ W2t) {
  __shared__ float tile[32][33];
  const int tx = threadIdx.x & 31, ty = threadIdx.x >> 5;  // ty 0..7
  const int k0 = blockIdx.x * 32, n0 = blockIdx.y * 32;
#pragma unroll
  for (int r = ty; r < 32; r += 8)
    tile[r][tx] = W2[(size_t)(k0 + r) * HID + n0 + tx];
  __syncthreads();
#pragma unroll
  for (int r = ty; r < 32; r += 8)
    W2t[(size_t)(n0 + r) * HID + k0 + tx] = f2bf(tile[tx][r]);
}

// ---------------------------------------------------------------------------
// Kernel 2: h = relu(h1 @ W2 + b2), bf16 MFMA (m97 structure).
// BM=128 BN=64 BK=32, 256 thr = 4 waves (2x2), wave tile 64x32,
// global_load_lds width-16 staging, 2-barrier loop, grid 512 = 2 blocks/CU.
// ---------------------------------------------------------------------------
#define BM 128
#define BN 64
#define BK 32

__global__ __launch_bounds__(256) void k_gemm2_mfma(const ushort* __restrict__ A,
                                                    const ushort* __restrict__ Bt,
                                                    const float* __restrict__ b2,
                                                    ushort* __restrict__ H) {
  __shared__ ushort As[BM * BK];   // [m][k] linear
  __shared__ ushort Bs[BN * BK];   // [n][k] linear
  const int t = threadIdx.x;
  const int wave = t >> 6, lane = t & 63;
  const int l15 = lane & 15, lhi = lane >> 4;        // frag row-group
  const int wr = wave >> 1, wc = wave & 1;           // 2x2 wave grid
  const int bm = blockIdx.y * BM;
  const int bn = blockIdx.x * BN;

  const int srow = t >> 2;           // 0..63
  const int scol = (t & 3) * 8;      // k element offset
  const ushort* gA0 = A  + (size_t)(bm + srow) * HID + scol;
  const ushort* gA1 = gA0 + (size_t)64 * HID;
  const ushort* gB  = Bt + (size_t)(bn + srow) * HID + scol;
  ushort* lA0 = As + wave * 512;            // wave-uniform, 1024B per wave
  ushort* lA1 = As + 2048 + wave * 512;
  ushort* lB  = Bs + wave * 512;

  f32x4 acc[4][2];
#pragma unroll
  for (int mi = 0; mi < 4; ++mi)
#pragma unroll
    for (int ni = 0; ni < 2; ++ni) acc[mi][ni] = {0.f, 0.f, 0.f, 0.f};

  for (int k0 = 0; k0 < HID; k0 += BK) {
    async16(gA0 + k0, lA0);
    async16(gA1 + k0, lA1);
    async16(gB  + k0, lB);
    __syncthreads();                 // vmcnt(0) drained by compiler -> LDS ready
    bf16x8 af[4], bfr[2];
#pragma unroll
    for (int mi = 0; mi < 4; ++mi)
      af[mi] = *(const bf16x8*)&As[(wr * 64 + mi * 16 + l15) * BK + lhi * 8];
#pragma unroll
    for (int ni = 0; ni < 2; ++ni)
      bfr[ni] = *(const bf16x8*)&Bs[(wc * 32 + ni * 16 + l15) * BK + lhi * 8];
#pragma unroll
    for (int mi = 0; mi < 4; ++mi)
#pragma unroll
      for (int ni = 0; ni < 2; ++ni)
        acc[mi][ni] = __builtin_amdgcn_mfma_f32_16x16x32_bf16(af[mi], bfr[ni],
                                                              acc[mi][ni], 0, 0, 0);
    __syncthreads();                 // all reads done before next stage overwrites
  }

  // Epilogue: bias + relu -> bf16. C/D layout: col=lane&15, row=(lane>>4)*4+j.
#pragma unroll
  for (int ni = 0; ni < 2; ++ni) {
    const int col = bn + wc * 32 + ni * 16 + l15;
    const float bias = b2[col];
#pragma unroll
    for (int mi = 0; mi < 4; ++mi) {
      const int row = bm + wr * 64 + mi * 16 + lhi * 4;
#pragma unroll
      for (int j = 0; j < 4; ++j)
        H[(size_t)(row + j) * HID + col] = f2bf(fmaxf(acc[mi][ni][j] + bias, 0.f));
    }
  }
}

// ---------------------------------------------------------------------------
// Kernel 3: heads (reads bf16 h). One wave per row.
// ---------------------------------------------------------------------------
__global__ __launch_bounds__(256) void k_heads(const ushort* __restrict__ Hm,
                                               const float* __restrict__ Wss,
                                               const float* __restrict__ bss,
                                               const float* __restrict__ Wang,
                                               const float* __restrict__ bang,
                                               const float* __restrict__ Wc,
                                               float* __restrict__ ssO,
                                               float* __restrict__ angO,
                                               float* __restrict__ ci,
                                               float* __restrict__ cj) {
  const int lane = threadIdx.x & 63;
  const int row  = blockIdx.x * 4 + (threadIdx.x >> 6);
  const ushort* hr = Hm + (size_t)row * HID;
  const uint4 hq = *(const uint4*)&hr[lane * 8];   // 8 bf16
  float hv[8];
  hv[0] = bf2f((ushort)(hq.x & 0xffff)); hv[1] = bf2f((ushort)(hq.x >> 16));
  hv[2] = bf2f((ushort)(hq.y & 0xffff)); hv[3] = bf2f((ushort)(hq.y >> 16));
  hv[4] = bf2f((ushort)(hq.z & 0xffff)); hv[5] = bf2f((ushort)(hq.z >> 16));
  hv[6] = bf2f((ushort)(hq.w & 0xffff)); hv[7] = bf2f((ushort)(hq.w >> 16));

  float s0 = 0, s1 = 0, s2 = 0, a0 = 0, a1 = 0, c0 = 0, c1 = 0;
#pragma unroll
  for (int j = 0; j < 8; ++j) {
    const int k = lane * 8 + j;
    const float h = hv[j];
    s0 += h * Wss[k * 3 + 0];
    s1 += h * Wss[k * 3 + 1];
    s2 += h * Wss[k * 3 + 2];
    a0 += h * Wang[k * 2 + 0];
    a1 += h * Wang[k * 2 + 1];
    c0 += h * Wc[k];
    c1 += h * Wc[HID + k];
  }
#pragma unroll
  for (int off = 32; off > 0; off >>= 1) {
    s0 += __shfl_down(s0, off); s1 += __shfl_down(s1, off); s2 += __shfl_down(s2, off);
    a0 += __shfl_down(a0, off); a1 += __shfl_down(a1, off);
    c0 += __shfl_down(c0, off); c1 += __shfl_down(c1, off);
  }
  if (lane == 0) {
    const float l0 = s0 + bss[0], l1 = s1 + bss[1], l2 = s2 + bss[2];
    const float mx = fmaxf(l0, fmaxf(l1, l2));
    const float e0 = expf(l0 - mx), e1 = expf(l1 - mx), e2 = expf(l2 - mx);
    const float inv = 1.f / (e0 + e1 + e2);
    ssO[row * 3 + 0] = e0 * inv;
    ssO[row * 3 + 1] = e1 * inv;
    ssO[row * 3 + 2] = e2 * inv;
    angO[row * 2 + 0] = a0 + bang[0];
    angO[row * 2 + 1] = a1 + bang[1];
    ci[row] = c0;
    cj[row] = c1;
  }
}

// ---------------------------------------------------------------------------
// Kernel 4: contact = sigmoid(ci + cj + bc). 67 MB write, HBM-bound.
// ---------------------------------------------------------------------------
__global__ __launch_bounds__(256) void k_contact(const float* __restrict__ ci,
                                                 const float* __restrict__ cj,
                                                 const float* __restrict__ bc,
                                                 float* __restrict__ out) {
  const int row = blockIdx.x;
  const int b   = row >> 11;
  const float base = ci[row] + bc[0];
  const float* cjb = cj + ((size_t)b << 11);
  float* orow = out + (size_t)row * LSEQ;
  const int j0 = threadIdx.x * 8;
  const float4 c0 = *(const float4*)&cjb[j0];
  const float4 c1 = *(const float4*)&cjb[j0 + 4];
  float4 r0, r1;
  r0.x = 1.f / (1.f + __expf(-(base + c0.x)));
  r0.y = 1.f / (1.f + __expf(-(base + c0.y)));
  r0.z = 1.f / (1.f + __expf(-(base + c0.z)));
  r0.w = 1.f / (1.f + __expf(-(base + c0.w)));
  r1.x = 1.f / (1.f + __expf(-(base + c1.x)));
  r1.y = 1.f / (1.f + __expf(-(base + c1.y)));
  r1.z = 1.f / (1.f + __expf(-(base + c1.z)));
  r1.w = 1.f / (1.f + __expf(-(base + c1.w)));
  *(float4*)&orow[j0]     = r0;
  *(float4*)&orow[j0 + 4] = r1;
}

// ---------------------------------------------------------------------------
extern "C" void kernel_launch(void* const* d_in, const int* in_sizes, int n_in,
                              void* d_out, int out_size, void* d_ws, size_t ws_size,
                              hipStream_t stream) {
  const float* X    = (const float*)d_in[0];
  const float* W1   = (const float*)d_in[1];
  const float* b1   = (const float*)d_in[2];
  const float* W2   = (const float*)d_in[3];
  const float* b2   = (const float*)d_in[4];
  const float* Wss  = (const float*)d_in[5];
  const float* bss  = (const float*)d_in[6];
  const float* Wang = (const float*)d_in[7];
  const float* bang = (const float*)d_in[8];
  const float* Wc   = (const float*)d_in[9];
  const float* bc   = (const float*)d_in[10];

  float* out     = (float*)d_out;
  float* ssO     = out;                         // [8192,3]
  float* angO    = out + 24576;                 // [8192,2]
  float* contact = out + 40960;                 // [4,2048,2048]

  // Scratch lives in the not-yet-written contact region (fully overwritten
  // by k_contact last). ci/cj (64 KB) in d_ws.
  ushort* h1  = (ushort*)contact;                                  // 8 MB
  ushort* hh  = (ushort*)(contact + (size_t)2 * 1024 * 1024);      // 8 MB
  ushort* W2t = (ushort*)(contact + (size_t)4 * 1024 * 1024);      // 512 KB
  float* ci = (float*)d_ws;
  float* cj = ci + MROWS;

  k_cvtW2<<<dim3(16, 16), 256, 0, stream>>>(W2, W2t);
  k_enc1<<<MROWS / 16, 256, 0, stream>>>(X, W1, b1, h1);
  k_gemm2_mfma<<<dim3(HID / BN, MROWS / BM), 256, 0, stream>>>(h1, W2t, b2, hh);
  k_heads<<<MROWS / 4, 256, 0, stream>>>(hh, Wss, bss, Wang, bang, Wc,
                                         ssO, angO, ci, cj);
  k_contact<<<MROWS, 256, 0, stream>>>(ci, cj, bc, contact);
}

// Round 4
// 50.811 us; speedup vs baseline: 1.9997x; 1.1527x over previous
//
#include <hip/hip_runtime.h>
#include <cstdint>
#include <cstddef>

#define SEQD 20
#define HID  512
#define LSEQ 2048
#define MROWS 8192
#define GBM 128
#define GBN 128
#define GBK 64

typedef __attribute__((ext_vector_type(4))) float f32x4;
typedef __attribute__((ext_vector_type(8))) short bf16x8;

__device__ __forceinline__ ushort f2bf(float f) {
  union { float f; unsigned u; } v; v.f = f;
  unsigned r = v.u + 0x7fffu + ((v.u >> 16) & 1u);   // RNE
  return (ushort)(r >> 16);
}
// XOR-swizzle of a byte offset b (0..127) within a 128B k-stripe, keyed by row.
// Involution; moves only 16B-slot bits (4..6). Applied identically at global
// write time (pre-swizzle) and at ds_read time; LDS staging copies linearly
// (rule #21: both-sides-or-neither with global_load_lds).
__device__ __forceinline__ int swzb(int row, int b) {
  return (b & 0x0F) | ((b ^ ((row & 7) << 4)) & 0x70);
}
// async global->LDS, 16B/lane. lds ptr must be wave-uniform (HW adds lane*16).
__device__ __forceinline__ void async16(const ushort* g, ushort* l) {
  __builtin_amdgcn_global_load_lds(
      (const __attribute__((address_space(1))) unsigned*)g,
      (__attribute__((address_space(3))) unsigned*)l, 16, 0, 0);
}

// ---------------------------------------------------------------------------
// Kernel 1 (prep): blocks [0,512): h1 = relu(X@W1+b1) -> bf16, PRE-SWIZZLED.
//                  blocks [512,768): W2t[n][k] bf16 transpose, PRE-SWIZZLED.
// ---------------------------------------------------------------------------
__global__ __launch_bounds__(256) void k_prep(const float* __restrict__ X,
                                              const float* __restrict__ W1,
                                              const float* __restrict__ b1,
                                              const float* __restrict__ W2,
                                              ushort* __restrict__ h1,
                                              ushort* __restrict__ W2t) {
  __shared__ float Xs[16][SEQD + 1];
  __shared__ float tile[32][33];
  const int t = threadIdx.x;
  if (blockIdx.x < 512) {
    // ---- enc1 ----
    const int base = blockIdx.x * 16;
    for (int i = t; i < 16 * SEQD; i += 256) Xs[i / SEQD][i % SEQD] = X[base * SEQD + i];
    __syncthreads();
    const int m0 = (t >> 6) * 4;
    const int nl = (t & 63) * 4;
    float4 acc[4][2];
#pragma unroll
    for (int mi = 0; mi < 4; ++mi) {
      acc[mi][0] = *(const float4*)&b1[nl];
      acc[mi][1] = *(const float4*)&b1[nl + 256];
    }
#pragma unroll
    for (int k = 0; k < SEQD; ++k) {
      const float4 w0 = *(const float4*)&W1[k * HID + nl];
      const float4 w1 = *(const float4*)&W1[k * HID + nl + 256];
#pragma unroll
      for (int mi = 0; mi < 4; ++mi) {
        const float xv = Xs[m0 + mi][k];
        acc[mi][0].x += xv * w0.x; acc[mi][0].y += xv * w0.y;
        acc[mi][0].z += xv * w0.z; acc[mi][0].w += xv * w0.w;
        acc[mi][1].x += xv * w1.x; acc[mi][1].y += xv * w1.y;
        acc[mi][1].z += xv * w1.z; acc[mi][1].w += xv * w1.w;
      }
    }
#pragma unroll
    for (int mi = 0; mi < 4; ++mi) {
      const int m = base + m0 + mi;
#pragma unroll
      for (int g = 0; g < 2; ++g) {
        const float4 r = acc[mi][g];
        ushort4 o;
        o.x = f2bf(fmaxf(r.x, 0.f)); o.y = f2bf(fmaxf(r.y, 0.f));
        o.z = f2bf(fmaxf(r.z, 0.f)); o.w = f2bf(fmaxf(r.w, 0.f));
        const int k = nl + g * 256;
        const int sb = swzb(m, (k & 63) * 2);            // 8B-aligned slot pos
        *(ushort4*)&h1[(size_t)m * HID + (k & ~63) + (sb >> 1)] = o;
      }
    }
  } else {
    // ---- W2 [k][n] f32 -> W2t [n][k] bf16, swizzled ----
    const int c = blockIdx.x - 512;
    const int k0 = (c & 15) * 32, n0 = (c >> 4) * 32;
    const int tx = t & 31, ty = t >> 5;
#pragma unroll
    for (int r = ty; r < 32; r += 8)
      tile[r][tx] = W2[(size_t)(k0 + r) * HID + n0 + tx];
    __syncthreads();
#pragma unroll
    for (int r = ty; r < 32; r += 8) {
      const int n = n0 + r, k = k0 + tx;
      const int sb = swzb(n, (k & 63) * 2);
      W2t[(size_t)n * HID + (k & ~63) + (sb >> 1)] = f2bf(tile[tx][r]);
    }
  }
}

// ---------------------------------------------------------------------------
// Kernel 2: gemm2 + fused heads. BM=BN=128, BK=64, 4 waves (2x2, 64x64 each),
// 2-phase double-buffered global_load_lds staging, swizzled ds_read_b128,
// epilogue computes per-row head partials (no h materialization).
// Hpart layout: [slice=8][8192 rows][8] f32; slice = xblk*2 + wc.
// (R3 bug: wc=0/1 waves cover different col halves of the SAME rows — they
//  must write distinct slices, not race on one.)
// ---------------------------------------------------------------------------
__global__ __launch_bounds__(256) void k_gemm_heads(const ushort* __restrict__ Aglob,
                                                    const ushort* __restrict__ Bglob,
                                                    const float* __restrict__ b2,
                                                    const float* __restrict__ Wss,
                                                    const float* __restrict__ Wang,
                                                    const float* __restrict__ Wc,
                                                    float* __restrict__ Hpart) {
  __shared__ ushort As[2][GBM * GBK];
  __shared__ ushort Bs[2][GBM * GBK];
  const int t = threadIdx.x;
  const int wave = t >> 6, lane = t & 63;
  const int l15 = lane & 15, lhi = lane >> 4;
  const int wr = wave >> 1, wc = wave & 1;
  // bijective XCD swizzle (nwg=256, 256%8==0): each XCD gets 32 contiguous ids
  const int swz = (blockIdx.x & 7) * 32 + (blockIdx.x >> 3);
  const int xblk = swz & 3, yblk = swz >> 2;
  const int bm = yblk * GBM, bn = xblk * GBN;
  const int srow = lane >> 3;          // 0..7
  const int scol = (lane & 7) * 8;     // element offset in k

  f32x4 acc[4][4];
#pragma unroll
  for (int mi = 0; mi < 4; ++mi)
#pragma unroll
    for (int ni = 0; ni < 4; ++ni) acc[mi][ni] = {0.f, 0.f, 0.f, 0.f};

#define STAGE(buf, k0)                                                         \
  {                                                                            \
    _Pragma("unroll")                                                          \
    for (int rd = 0; rd < 4; ++rd) {                                           \
      const int r = rd * 32 + wave * 8 + srow;                                 \
      const int lo = rd * 2048 + wave * 512; /* ushort units, wave-uniform */  \
      async16(Aglob + (size_t)(bm + r) * HID + (k0) + scol, &As[buf][lo]);     \
      async16(Bglob + (size_t)(bn + r) * HID + (k0) + scol, &Bs[buf][lo]);     \
    }                                                                          \
  }

#define COMPUTE(buf)                                                           \
  {                                                                            \
    _Pragma("unroll")                                                          \
    for (int kk = 0; kk < 2; ++kk) {                                           \
      bf16x8 af[4], bff[4];                                                    \
      _Pragma("unroll")                                                        \
      for (int mi = 0; mi < 4; ++mi) {                                         \
        const int row = wr * 64 + mi * 16 + l15;                               \
        af[mi] = *(const bf16x8*)&As[buf][(row * 128 + swzb(row, kk * 64 + lhi * 16)) >> 1]; \
      }                                                                        \
      _Pragma("unroll")                                                        \
      for (int ni = 0; ni < 4; ++ni) {                                         \
        const int rn = wc * 64 + ni * 16 + l15;                                \
        bff[ni] = *(const bf16x8*)&Bs[buf][(rn * 128 + swzb(rn, kk * 64 + lhi * 16)) >> 1]; \
      }                                                                        \
      _Pragma("unroll")                                                        \
      for (int mi = 0; mi < 4; ++mi)                                           \
        _Pragma("unroll")                                                      \
        for (int ni = 0; ni < 4; ++ni)                                         \
          acc[mi][ni] = __builtin_amdgcn_mfma_f32_16x16x32_bf16(af[mi], bff[ni], acc[mi][ni], 0, 0, 0); \
    }                                                                          \
  }

  STAGE(0, 0)
  __syncthreads();
#pragma unroll
  for (int kt = 0; kt < 8; ++kt) {
    if (kt < 7) STAGE((kt + 1) & 1, (kt + 1) * GBK)
    COMPUTE(kt & 1)
    __syncthreads();   // drains vmcnt (next buf ready) + WAR for buf reuse
  }

  // ---- epilogue: bias+relu, head partials, 16-lane reduce, write Hpart ----
  float bias[4], ws0[4], ws1[4], ws2[4], wa0[4], wa1[4], wc0[4], wc1[4];
#pragma unroll
  for (int ni = 0; ni < 4; ++ni) {
    const int col = bn + wc * 64 + ni * 16 + l15;
    bias[ni] = b2[col];
    ws0[ni] = Wss[col * 3 + 0]; ws1[ni] = Wss[col * 3 + 1]; ws2[ni] = Wss[col * 3 + 2];
    wa0[ni] = Wang[col * 2 + 0]; wa1[ni] = Wang[col * 2 + 1];
    wc0[ni] = Wc[col]; wc1[ni] = Wc[HID + col];
  }
  const int slice = xblk * 2 + wc;     // 8 distinct col-slices of HID=512
#pragma unroll
  for (int mi = 0; mi < 4; ++mi) {
#pragma unroll
    for (int j = 0; j < 4; ++j) {
      float p0 = 0, p1 = 0, p2 = 0, p3 = 0, p4 = 0, p5 = 0, p6 = 0;
#pragma unroll
      for (int ni = 0; ni < 4; ++ni) {
        const float v = fmaxf(acc[mi][ni][j] + bias[ni], 0.f);
        p0 += v * ws0[ni]; p1 += v * ws1[ni]; p2 += v * ws2[ni];
        p3 += v * wa0[ni]; p4 += v * wa1[ni];
        p5 += v * wc0[ni]; p6 += v * wc1[ni];
      }
#pragma unroll
      for (int m = 1; m <= 8; m <<= 1) {
        p0 += __shfl_xor(p0, m); p1 += __shfl_xor(p1, m); p2 += __shfl_xor(p2, m);
        p3 += __shfl_xor(p3, m); p4 += __shfl_xor(p4, m);
        p5 += __shfl_xor(p5, m); p6 += __shfl_xor(p6, m);
      }
      if (l15 == 0) {
        const int row = bm + wr * 64 + mi * 16 + lhi * 4 + j;
        float* hp = &Hpart[((size_t)slice * MROWS + row) * 8];
        hp[0] = p0; hp[1] = p1; hp[2] = p2; hp[3] = p3;
        hp[4] = p4; hp[5] = p5; hp[6] = p6;
      }
    }
  }
#undef STAGE
#undef COMPUTE
}

// ---------------------------------------------------------------------------
// Kernel 3: finish heads. One thread per row: sum 8 partials, softmax, write.
// ---------------------------------------------------------------------------
__global__ __launch_bounds__(256) void k_finish(const float* __restrict__ Hpart,
                                                const float* __restrict__ bss,
                                                const float* __restrict__ bang,
                                                float* __restrict__ ssO,
                                                float* __restrict__ angO,
                                                float* __restrict__ ci,
                                                float* __restrict__ cj) {
  const int row = blockIdx.x * 256 + threadIdx.x;
  float s0 = 0, s1 = 0, s2 = 0, a0 = 0, a1 = 0, c0 = 0, c1 = 0;
#pragma unroll
  for (int xb = 0; xb < 8; ++xb) {
    const float* hp = &Hpart[((size_t)xb * MROWS + row) * 8];
    s0 += hp[0]; s1 += hp[1]; s2 += hp[2];
    a0 += hp[3]; a1 += hp[4];
    c0 += hp[5]; c1 += hp[6];
  }
  const float l0 = s0 + bss[0], l1 = s1 + bss[1], l2 = s2 + bss[2];
  const float mx = fmaxf(l0, fmaxf(l1, l2));
  const float e0 = __expf(l0 - mx), e1 = __expf(l1 - mx), e2 = __expf(l2 - mx);
  const float inv = 1.f / (e0 + e1 + e2);
  ssO[row * 3 + 0] = e0 * inv;
  ssO[row * 3 + 1] = e1 * inv;
  ssO[row * 3 + 2] = e2 * inv;
  angO[row * 2 + 0] = a0 + bang[0];
  angO[row * 2 + 1] = a1 + bang[1];
  ci[row] = c0;
  cj[row] = c1;
}

// ---------------------------------------------------------------------------
// Kernel 4: contact = sigmoid(ci + cj + bc). 67 MB write, HBM-bound floor.
// ---------------------------------------------------------------------------
__global__ __launch_bounds__(256) void k_contact(const float* __restrict__ ci,
                                                 const float* __restrict__ cj,
                                                 const float* __restrict__ bc,
                                                 float* __restrict__ out) {
  const int row = blockIdx.x;
  const int b   = row >> 11;
  const float base = ci[row] + bc[0];
  const float* cjb = cj + ((size_t)b << 11);
  float* orow = out + (size_t)row * LSEQ;
  const int j0 = threadIdx.x * 8;
  const float4 c0 = *(const float4*)&cjb[j0];
  const float4 c1 = *(const float4*)&cjb[j0 + 4];
  float4 r0, r1;
  r0.x = 1.f / (1.f + __expf(-(base + c0.x)));
  r0.y = 1.f / (1.f + __expf(-(base + c0.y)));
  r0.z = 1.f / (1.f + __expf(-(base + c0.z)));
  r0.w = 1.f / (1.f + __expf(-(base + c0.w)));
  r1.x = 1.f / (1.f + __expf(-(base + c1.x)));
  r1.y = 1.f / (1.f + __expf(-(base + c1.y)));
  r1.z = 1.f / (1.f + __expf(-(base + c1.z)));
  r1.w = 1.f / (1.f + __expf(-(base + c1.w)));
  *(float4*)&orow[j0]     = r0;
  *(float4*)&orow[j0 + 4] = r1;
}

// ---------------------------------------------------------------------------
extern "C" void kernel_launch(void* const* d_in, const int* in_sizes, int n_in,
                              void* d_out, int out_size, void* d_ws, size_t ws_size,
                              hipStream_t stream) {
  const float* X    = (const float*)d_in[0];
  const float* W1   = (const float*)d_in[1];
  const float* b1   = (const float*)d_in[2];
  const float* W2   = (const float*)d_in[3];
  const float* b2   = (const float*)d_in[4];
  const float* Wss  = (const float*)d_in[5];
  const float* bss  = (const float*)d_in[6];
  const float* Wang = (const float*)d_in[7];
  const float* bang = (const float*)d_in[8];
  const float* Wc   = (const float*)d_in[9];
  const float* bc   = (const float*)d_in[10];

  float* out     = (float*)d_out;
  float* ssO     = out;                         // [8192,3]
  float* angO    = out + 24576;                 // [8192,2]
  float* contact = out + 40960;                 // [4,2048,2048] = 64MB

  // Scratch inside the not-yet-written contact region (k_contact overwrites
  // all of it last). ci/cj (64 KB) in d_ws.
  ushort* h1    = (ushort*)contact;                        // 8 MB  (swizzled)
  ushort* W2t   = (ushort*)(contact + 2 * 1024 * 1024);    // 512 KB (swizzled)
  float*  Hpart = contact + 3 * 1024 * 1024;               // 2 MB (8 slices)
  float* ci = (float*)d_ws;
  float* cj = ci + MROWS;

  k_prep<<<768, 256, 0, stream>>>(X, W1, b1, W2, h1, W2t);
  k_gemm_heads<<<256, 256, 0, stream>>>(h1, W2t, b2, Wss, Wang, Wc, Hpart);
  k_finish<<<MROWS / 256, 256, 0, stream>>>(Hpart, bss, bang, ssO, angO, ci, cj);
  k_contact<<<MROWS, 256, 0, stream>>>(ci, cj, bc, contact);
}